// Round 4
// baseline (11079.778 us; speedup 1.0000x reference)
//
#include <hip/hip_runtime.h>
#include <hip/hip_bf16.h>

#define N_NODES 4096
#define N_EDGES 16384
#define N_GRAPHS 16
#define HD 128   // hidden dim

typedef __hip_bfloat16 bf16;

// dtype-flexible load: F32 -> read float32, else read bf16 and widen
template <bool F32>
static __device__ __forceinline__ float ld(const void* p, int i) {
    if (F32) return ((const float*)p)[i];
    return __bfloat162float(((const bf16*)p)[i]);
}

static __device__ __forceinline__ float wave_sum(float v) {
#pragma unroll
    for (int off = 1; off < 64; off <<= 1) v += __shfl_xor(v, off, 64);
    return v;
}

// ---- detect input storage dtype from edge_attr bit patterns ------------
// f32 storage: even 16-bit words are low-mantissa bits (uniform random) ->
// ~12% have bf16-exponent >= 224. bf16 storage: N(0,1) values, exp <= ~130.
__global__ __launch_bounds__(256) void detect_k(const unsigned short* __restrict__ raw,
                                                int* __restrict__ flag) {
    __shared__ int cnt_s;
    if (threadIdx.x == 0) cnt_s = 0;
    __syncthreads();
    int c = 0;
    for (int i = threadIdx.x; i < 2048; i += 256) {
        unsigned short u = raw[2 * i];
        int e = (u >> 7) & 0xFF;
        if (e >= 224) ++c;
    }
    atomicAdd(&cnt_s, c);
    __syncthreads();
    if (threadIdx.x == 0) *flag = (cnt_s > 16) ? 1 : 0;
}

// ---- count incoming edges per node -------------------------------------
__global__ __launch_bounds__(256) void count_k(const int* __restrict__ dst, float* __restrict__ cnt) {
    int e = blockIdx.x * 256 + threadIdx.x;
    atomicAdd(&cnt[dst[e]], 1.0f);
}

// ---- layer 1 edge kernel (in_c = 3) ------------------------------------
template <bool F32>
__global__ __launch_bounds__(128) void l1_edge(
    const int* __restrict__ flag, const void* __restrict__ x,
    const int* __restrict__ src, const int* __restrict__ dst, const void* __restrict__ ea,
    const void* __restrict__ w1, const void* __restrict__ b1,
    const void* __restrict__ w2, const void* __restrict__ b2, float* __restrict__ agg) {
    if ((*flag != 0) != F32) return;
    __shared__ float h[4][HD];
    __shared__ float xsrc[4][3];
    const int o = threadIdx.x;
    const int e0 = blockIdx.x * 4;
#pragma unroll
    for (int q = 0; q < 4; ++q) {
        float s = ld<F32>(b1, o);
#pragma unroll
        for (int j = 0; j < 4; ++j) s = fmaf(ld<F32>(ea, (e0 + q) * 4 + j), ld<F32>(w1, j * HD + o), s);
        h[q][o] = fmaxf(s, 0.0f);
    }
    if (o < 12) { int q = o / 3, i = o % 3; xsrc[q][i] = ld<F32>(x, src[e0 + q] * 3 + i); }
    __syncthreads();
    float acc[4] = {0.f, 0.f, 0.f, 0.f};
    for (int i = 0; i < 3; ++i) {
        float bb = ld<F32>(b2, i * HD + o);
        float w[4] = {bb, bb, bb, bb};
        for (int k = 0; k < HD; ++k) {
            float w2v = ld<F32>(w2, k * 384 + i * HD + o);
#pragma unroll
            for (int q = 0; q < 4; ++q) w[q] = fmaf(h[q][k], w2v, w[q]);
        }
#pragma unroll
        for (int q = 0; q < 4; ++q) acc[q] = fmaf(xsrc[q][i], w[q], acc[q]);
    }
#pragma unroll
    for (int q = 0; q < 4; ++q) atomicAdd(&agg[dst[e0 + q] * HD + o], acc[q]);
}

// ---- layer-1 node update (IN PLACE on agg): agg := relu(LN(agg/cnt + x@root + bias))
template <bool F32>
__global__ __launch_bounds__(128) void node_update_l1(
    const int* __restrict__ flag, float* __restrict__ agg, const float* __restrict__ cnt,
    const void* __restrict__ x, const void* __restrict__ root, const void* __restrict__ bias,
    const void* __restrict__ lng, const void* __restrict__ lnb) {
    if ((*flag != 0) != F32) return;
    const int n = blockIdx.x, o = threadIdx.x;
    float s = ld<F32>(bias, o);
#pragma unroll
    for (int i = 0; i < 3; ++i) s = fmaf(ld<F32>(x, n * 3 + i), ld<F32>(root, i * HD + o), s);
    float v = agg[n * HD + o] / fmaxf(cnt[n], 1.0f) + s;
    __shared__ float red[2];
    float ws = wave_sum(v);
    if ((o & 63) == 0) red[o >> 6] = ws;
    __syncthreads();
    float m = (red[0] + red[1]) * (1.0f / HD);
    float d = v - m;
    float ws2 = wave_sum(d * d);
    __syncthreads();
    if ((o & 63) == 0) red[o >> 6] = ws2;
    __syncthreads();
    float var = (red[0] + red[1]) * (1.0f / HD);
    float y = d * rsqrtf(var + 1e-5f) * ld<F32>(lng, o) + ld<F32>(lnb, o);
    agg[n * HD + o] = fmaxf(y, 0.0f);
}

// ---- heavy fused edge-MLP + GEMM + scatter for layers 2/3 --------------
// he[e,k] = relu(ea@w1+b1); msg[e,o] = sum_k sum_i (he[e,k]*xs[e,i]) * w2[(k*128+i)*128+o]
//                                    + sum_i xs[e,i]*b2[i*128+o]
#define BM 32
template <bool F32>
__global__ __launch_bounds__(256) void gemm_scatter(
    const int* __restrict__ flag, const float* __restrict__ hprev,
    const void* __restrict__ ea, const void* __restrict__ w1, const void* __restrict__ b1,
    const void* __restrict__ w2, const void* __restrict__ b2,
    const int* __restrict__ src, const int* __restrict__ dst, float* __restrict__ agg) {
    if ((*flag != 0) != F32) return;
    __shared__ float he[BM][HD];
    __shared__ float xs[BM][HD];
    __shared__ float prod[BM][HD];
    const int t = threadIdx.x;
    const int e0 = blockIdx.x * BM;
#pragma unroll
    for (int c = 0; c < BM * HD / 256; ++c) {
        int flat = c * 256 + t;
        int le = flat >> 7, k = flat & 127;
        int e = e0 + le;
        float s = ld<F32>(b1, k);
#pragma unroll
        for (int j = 0; j < 4; ++j) s = fmaf(ld<F32>(ea, e * 4 + j), ld<F32>(w1, j * HD + k), s);
        he[le][k] = fmaxf(s, 0.0f);
        xs[le][k] = hprev[src[e] * HD + k];
    }
    const int o = t & 127;
    const int ty = t >> 7;  // 0..1, each owns BM/2 = 16 edges
    float acc[BM / 2];
#pragma unroll
    for (int e = 0; e < BM / 2; ++e) acc[e] = 0.0f;
    __syncthreads();
    for (int kt = 0; kt <= 128; ++kt) {
        const bool bias_blk = (kt == 128);
#pragma unroll
        for (int c = 0; c < BM * HD / 256; ++c) {
            int flat = c * 256 + t;
            int le = flat >> 7, i = flat & 127;
            prod[le][i] = (bias_blk ? 1.0f : he[le][kt]) * xs[le][i];
        }
        __syncthreads();
        const void* B = bias_blk ? b2 : w2;
        const int boff = bias_blk ? 0 : kt * 16384;
#pragma unroll 4
        for (int i = 0; i < 128; ++i) {
            float b = ld<F32>(B, boff + i * HD + o);
#pragma unroll
            for (int e = 0; e < BM / 2; ++e) acc[e] = fmaf(prod[ty * (BM / 2) + e][i], b, acc[e]);
        }
        __syncthreads();
    }
#pragma unroll
    for (int e = 0; e < BM / 2; ++e) {
        int eg = e0 + ty * (BM / 2) + e;
        atomicAdd(&agg[dst[eg] * HD + o], acc[e]);
    }
}

// ---- node update layers 2/3 (IN PLACE on agg): act 1 = elu, 2 = leaky_relu(0.01)
template <bool F32>
__global__ __launch_bounds__(128) void node_update(
    const int* __restrict__ flag, float* __restrict__ agg, const float* __restrict__ cnt,
    const float* __restrict__ hprev, const void* __restrict__ root, const void* __restrict__ bias,
    const void* __restrict__ lng, const void* __restrict__ lnb, int act) {
    if ((*flag != 0) != F32) return;
    const int n = blockIdx.x, o = threadIdx.x;
    __shared__ float hr[HD];
    hr[o] = hprev[n * HD + o];
    __syncthreads();
    float s = ld<F32>(bias, o);
#pragma unroll 8
    for (int k = 0; k < HD; ++k) s = fmaf(hr[k], ld<F32>(root, k * HD + o), s);
    float v = agg[n * HD + o] / fmaxf(cnt[n], 1.0f) + s;
    __shared__ float red[2];
    float ws = wave_sum(v);
    if ((o & 63) == 0) red[o >> 6] = ws;
    __syncthreads();
    float m = (red[0] + red[1]) * (1.0f / HD);
    float d = v - m;
    float ws2 = wave_sum(d * d);
    __syncthreads();
    if ((o & 63) == 0) red[o >> 6] = ws2;
    __syncthreads();
    float var = (red[0] + red[1]) * (1.0f / HD);
    float y = d * rsqrtf(var + 1e-5f) * ld<F32>(lng, o) + ld<F32>(lnb, o);
    if (act == 1) y = (y > 0.0f) ? y : expm1f(y);
    else y = (y > 0.0f) ? y : 0.01f * y;
    agg[n * HD + o] = y;
}

// ---- pooling (mean/max per graph) + linear head; OUTPUT IS F32 ---------
template <bool F32>
__global__ __launch_bounds__(128) void pool_head(
    const int* __restrict__ flag, const float* __restrict__ h3, const int* __restrict__ batch,
    const void* __restrict__ cont, const void* __restrict__ ls,
    const void* __restrict__ lin_w, const void* __restrict__ lin_b, float* __restrict__ out) {
    if ((*flag != 0) != F32) return;
    const int g = blockIdx.x, o = threadIdx.x;
    float s = 0.0f, mx = -1e30f;
    int c = 0;
    for (int n = 0; n < N_NODES; ++n) {
        if (batch[n] == g) {
            float v = h3[n * HD + o];
            s += v;
            mx = fmaxf(mx, v);
            ++c;
        }
    }
    __shared__ float xcat[2 * HD + 5];
    xcat[o] = s / fmaxf((float)c, 1.0f);
    xcat[HD + o] = (c > 0) ? mx : 0.0f;
    if (o < 4) xcat[2 * HD + o] = ld<F32>(cont, g * 4 + o);
    if (o == 0) xcat[2 * HD + 4] = ld<F32>(ls, g);
    __syncthreads();
    if (o < 2) {
        float r = ld<F32>(lin_b, o);
        for (int ri = 0; ri < 2 * HD + 5; ++ri) r = fmaf(xcat[ri], ld<F32>(lin_w, ri * 2 + o), r);
        out[g * 2 + o] = r;   // f32 output (reference output dtype is float32)
    }
}

extern "C" void kernel_launch(void* const* d_in, const int* in_sizes, int n_in,
                              void* d_out, int out_size, void* d_ws, size_t ws_size,
                              hipStream_t stream) {
    const void* x     = d_in[0];
    const int*  ei    = (const int*)d_in[1];
    const void* ea    = d_in[2];
    const int*  batch = (const int*)d_in[3];
    const void* cont  = d_in[4];
    const void* ls    = d_in[5];
    const void *c1_w1 = d_in[6],  *c1_b1 = d_in[7],  *c1_w2 = d_in[8],  *c1_b2 = d_in[9];
    const void *c1_rt = d_in[10], *c1_bs = d_in[11];
    const void *c2_w1 = d_in[12], *c2_b1 = d_in[13], *c2_w2 = d_in[14], *c2_b2 = d_in[15];
    const void *c2_rt = d_in[16], *c2_bs = d_in[17];
    const void *c3_w1 = d_in[18], *c3_b1 = d_in[19], *c3_w2 = d_in[20], *c3_b2 = d_in[21];
    const void *c3_rt = d_in[22], *c3_bs = d_in[23];
    const void *ln1g = d_in[24], *ln1b = d_in[25];
    const void *ln2g = d_in[26], *ln2b = d_in[27];
    const void *ln3g = d_in[28], *ln3b = d_in[29];
    const void *lin_w = d_in[30], *lin_b = d_in[31];
    float* out = (float*)d_out;

    // workspace layout — TOTAL 4.02 MB (flag 64B + cnt 16KB + 2 x 2MB ping-pong)
    int*   flag = (int*)d_ws;
    float* cnt  = (float*)((char*)d_ws + 64);
    float* bufA = cnt + N_NODES;            // N*128 f32: agg1 -> h1 -> agg3 -> h3
    float* bufB = bufA + N_NODES * HD;      // N*128 f32: agg2 -> h2
    const int* src = ei;
    const int* dst = ei + N_EDGES;

    detect_k<<<1, 256, 0, stream>>>((const unsigned short*)ea, flag);
    hipMemsetAsync(cnt, 0, N_NODES * sizeof(float), stream);
    count_k<<<N_EDGES / 256, 256, 0, stream>>>(dst, cnt);

    // ---- layer 1: aggregate into A, then A := relu(LN(A/cnt + x@root + b))
    hipMemsetAsync(bufA, 0, N_NODES * HD * sizeof(float), stream);
    l1_edge<false><<<N_EDGES / 4, 128, 0, stream>>>(flag, x, src, dst, ea, c1_w1, c1_b1, c1_w2, c1_b2, bufA);
    l1_edge<true ><<<N_EDGES / 4, 128, 0, stream>>>(flag, x, src, dst, ea, c1_w1, c1_b1, c1_w2, c1_b2, bufA);
    node_update_l1<false><<<N_NODES, 128, 0, stream>>>(flag, bufA, cnt, x, c1_rt, c1_bs, ln1g, ln1b);
    node_update_l1<true ><<<N_NODES, 128, 0, stream>>>(flag, bufA, cnt, x, c1_rt, c1_bs, ln1g, ln1b);

    // ---- layer 2: read A, aggregate into B, then B := elu(LN(B/cnt + A@root + b))
    hipMemsetAsync(bufB, 0, N_NODES * HD * sizeof(float), stream);
    gemm_scatter<false><<<N_EDGES / BM, 256, 0, stream>>>(flag, bufA, ea, c2_w1, c2_b1, c2_w2, c2_b2, src, dst, bufB);
    gemm_scatter<true ><<<N_EDGES / BM, 256, 0, stream>>>(flag, bufA, ea, c2_w1, c2_b1, c2_w2, c2_b2, src, dst, bufB);
    node_update<false><<<N_NODES, 128, 0, stream>>>(flag, bufB, cnt, bufA, c2_rt, c2_bs, ln2g, ln2b, 1);
    node_update<true ><<<N_NODES, 128, 0, stream>>>(flag, bufB, cnt, bufA, c2_rt, c2_bs, ln2g, ln2b, 1);

    // ---- layer 3: read B, aggregate into A, then A := leaky(LN(A/cnt + B@root + b))
    hipMemsetAsync(bufA, 0, N_NODES * HD * sizeof(float), stream);
    gemm_scatter<false><<<N_EDGES / BM, 256, 0, stream>>>(flag, bufB, ea, c3_w1, c3_b1, c3_w2, c3_b2, src, dst, bufA);
    gemm_scatter<true ><<<N_EDGES / BM, 256, 0, stream>>>(flag, bufB, ea, c3_w1, c3_b1, c3_w2, c3_b2, src, dst, bufA);
    node_update<false><<<N_NODES, 128, 0, stream>>>(flag, bufA, cnt, bufB, c3_rt, c3_bs, ln3g, ln3b, 2);
    node_update<true ><<<N_NODES, 128, 0, stream>>>(flag, bufA, cnt, bufB, c3_rt, c3_bs, ln3g, ln3b, 2);

    // ---- pool + head (f32 output)
    pool_head<false><<<N_GRAPHS, 128, 0, stream>>>(flag, bufA, batch, cont, ls, lin_w, lin_b, out);
    pool_head<true ><<<N_GRAPHS, 128, 0, stream>>>(flag, bufA, batch, cont, ls, lin_w, lin_b, out);
}

// Round 5
// 734.736 us; speedup vs baseline: 15.0799x; 15.0799x over previous
//
#include <hip/hip_runtime.h>
#include <hip/hip_bf16.h>

// Inputs proven f32 (R1: bf16-reading f32 gave NaN; R4: f32 path passed absmax=0).
// Output f32.

#define N_NODES 4096
#define N_EDGES 16384
#define N_GRAPHS 16
#define HD 128   // hidden dim
#define BM 64    // edges per block in MFMA gemm
#define LDB 136  // padded LDS row stride in bf16 elems (272 B: 16B-aligned, min-phase banks)

typedef unsigned short ushort_t;
typedef __attribute__((ext_vector_type(8))) short short8;  // 8 bf16 = 4 VGPR (MFMA A/B frag)
typedef __attribute__((ext_vector_type(4))) float f32x4;   // MFMA C/D frag

static __device__ __forceinline__ ushort_t f2b(float f) {
    __hip_bfloat16 h = __float2bfloat16(f);
    union { __hip_bfloat16 h; ushort_t u; } cv; cv.h = h; return cv.u;
}
static __device__ __forceinline__ float b2f(ushort_t u) {
    union { unsigned u; float f; } cv; cv.u = ((unsigned)u) << 16; return cv.f;
}

static __device__ __forceinline__ float wave_sum(float v) {
#pragma unroll
    for (int off = 1; off < 64; off <<= 1) v += __shfl_xor(v, off, 64);
    return v;
}

// ---- count incoming edges per node -------------------------------------
__global__ __launch_bounds__(256) void count_k(const int* __restrict__ dst, float* __restrict__ cnt) {
    int e = blockIdx.x * 256 + threadIdx.x;
    atomicAdd(&cnt[dst[e]], 1.0f);
}

// ---- layer 1 edge kernel (in_c = 3), f32 VALU (tiny) -------------------
__global__ __launch_bounds__(128) void l1_edge(
    const float* __restrict__ x, const int* __restrict__ src, const int* __restrict__ dst,
    const float* __restrict__ ea, const float* __restrict__ w1, const float* __restrict__ b1,
    const float* __restrict__ w2, const float* __restrict__ b2, float* __restrict__ agg) {
    __shared__ float h[4][HD];
    __shared__ float xsrc[4][3];
    const int o = threadIdx.x;
    const int e0 = blockIdx.x * 4;
#pragma unroll
    for (int q = 0; q < 4; ++q) {
        float s = b1[o];
#pragma unroll
        for (int j = 0; j < 4; ++j) s = fmaf(ea[(e0 + q) * 4 + j], w1[j * HD + o], s);
        h[q][o] = fmaxf(s, 0.0f);
    }
    if (o < 12) { int q = o / 3, i = o % 3; xsrc[q][i] = x[src[e0 + q] * 3 + i]; }
    __syncthreads();
    float acc[4] = {0.f, 0.f, 0.f, 0.f};
    for (int i = 0; i < 3; ++i) {
        float bb = b2[i * HD + o];
        float w[4] = {bb, bb, bb, bb};
        for (int k = 0; k < HD; ++k) {
            float w2v = w2[k * 384 + i * HD + o];
#pragma unroll
            for (int q = 0; q < 4; ++q) w[q] = fmaf(h[q][k], w2v, w[q]);
        }
#pragma unroll
        for (int q = 0; q < 4; ++q) acc[q] = fmaf(xsrc[q][i], w[q], acc[q]);
    }
#pragma unroll
    for (int q = 0; q < 4; ++q) atomicAdd(&agg[dst[e0 + q] * HD + o], acc[q]);
}

// ---- layer-1 node update (IN PLACE): agg := relu(LN(agg/cnt + x@root + b))
__global__ __launch_bounds__(128) void node_update_l1(
    float* __restrict__ agg, const float* __restrict__ cnt, const float* __restrict__ x,
    const float* __restrict__ root, const float* __restrict__ bias,
    const float* __restrict__ lng, const float* __restrict__ lnb) {
    const int n = blockIdx.x, o = threadIdx.x;
    float s = bias[o];
#pragma unroll
    for (int i = 0; i < 3; ++i) s = fmaf(x[n * 3 + i], root[i * HD + o], s);
    float v = agg[n * HD + o] / fmaxf(cnt[n], 1.0f) + s;
    __shared__ float red[2];
    float ws = wave_sum(v);
    if ((o & 63) == 0) red[o >> 6] = ws;
    __syncthreads();
    float m = (red[0] + red[1]) * (1.0f / HD);
    float d = v - m;
    float ws2 = wave_sum(d * d);
    __syncthreads();
    if ((o & 63) == 0) red[o >> 6] = ws2;
    __syncthreads();
    float var = (red[0] + red[1]) * (1.0f / HD);
    float y = d * rsqrtf(var + 1e-5f) * lng[o] + lnb[o];
    agg[n * HD + o] = fmaxf(y, 0.0f);
}

// ---- one-time transpose+convert: w2t[kt][o][i] = bf16(w2[kt][i][o]); kt=128 slab = b2
__global__ __launch_bounds__(256) void w2t_prep(const float* __restrict__ w2,
                                                const float* __restrict__ b2,
                                                ushort_t* __restrict__ w2t) {
    __shared__ ushort_t tile[HD][LDB];
    const int kt = blockIdx.x;  // 0..128
    const int t = threadIdx.x;
    const float* srcp = (kt < HD) ? (w2 + kt * HD * HD) : b2;
    for (int c = 0; c < 64; ++c) {
        int flat = c * 256 + t;          // 0..16383, coalesced over o
        int i = flat >> 7, o = flat & 127;
        tile[o][i] = f2b(srcp[i * HD + o]);
    }
    __syncthreads();
    uint4* outp = (uint4*)(w2t + kt * HD * HD);
    for (int c = 0; c < 8; ++c) {
        int f = c * 256 + t;             // 16B-chunk index, coalesced
        int o = f >> 4, i0 = (f & 15) * 8;
        outp[f] = *(const uint4*)&tile[o][i0];
    }
}

// ---- heavy layers 2/3: MFMA GEMM + he-scaling + atomic scatter ---------
// P[e, kt, o] = xs[e,:] (bf16) @ w2t[kt][o,:] (bf16);  msg[e,o] = sum_kt he[e,kt]*P
// A-frags (xs) static over the whole kt loop; he applied on C-frags in f32.
__global__ __launch_bounds__(256) void gemm_mfma(
    const float* __restrict__ hprev, const float* __restrict__ ea,
    const float* __restrict__ w1, const float* __restrict__ b1,
    const ushort_t* __restrict__ w2t,
    const int* __restrict__ src, const int* __restrict__ dst,
    float* __restrict__ agg) {
    __shared__ ushort_t Bs[HD][LDB];      // 34,816 B : w2t slab (transposed, bf16)
    __shared__ ushort_t Xs[BM][LDB];      // 17,408 B : gathered source features (bf16)
    __shared__ ushort_t HeT[HD + 1][BM];  // 16,512 B : edge-MLP outputs, [kt][e]
    __shared__ float    eas[BM][4];

    const int t = threadIdx.x;
    const int wave = t >> 6, lane = t & 63;
    const int quad = lane >> 4, l16 = lane & 15;
    const int e0 = blockIdx.x * BM;

    // stage edge attrs
    eas[t >> 2][t & 3] = ea[(e0 + (t >> 2)) * 4 + (t & 3)];

    // stage xs: thread -> (edge t>>2, 32 cols), f32 -> bf16
    {
        const int le = t >> 2, i0 = (t & 3) * 32;
        const float* rp = hprev + src[e0 + le] * HD + i0;
        ushort_t tmp[32];
#pragma unroll
        for (int c = 0; c < 8; ++c) {
            float4 v = ((const float4*)rp)[c];
            tmp[c * 4 + 0] = f2b(v.x); tmp[c * 4 + 1] = f2b(v.y);
            tmp[c * 4 + 2] = f2b(v.z); tmp[c * 4 + 3] = f2b(v.w);
        }
#pragma unroll
        for (int c = 0; c < 4; ++c)
            *(uint4*)&Xs[le][i0 + c * 8] = *(const uint4*)&tmp[c * 8];
    }
    __syncthreads();

    // A-frags: a[mi][kb], lane holds A[m=l16][k = kb*32 + quad*8 + j]
    short8 afrag[4][4];
#pragma unroll
    for (int mi = 0; mi < 4; ++mi)
#pragma unroll
        for (int kb = 0; kb < 4; ++kb)
            afrag[mi][kb] = *(const short8*)&Xs[mi * 16 + l16][kb * 32 + quad * 8];

    // edge MLP -> HeT[kt][e] (bf16); kt=128 slab = 1.0 (bias term)
    {
        const int e = t & 63;
        const float a0 = eas[e][0], a1 = eas[e][1], a2 = eas[e][2], a3 = eas[e][3];
        for (int kt = t >> 6; kt < HD; kt += 4) {
            float s = b1[kt];
            s = fmaf(a0, w1[0 * HD + kt], s);
            s = fmaf(a1, w1[1 * HD + kt], s);
            s = fmaf(a2, w1[2 * HD + kt], s);
            s = fmaf(a3, w1[3 * HD + kt], s);
            HeT[kt][e] = f2b(fmaxf(s, 0.0f));
        }
        if ((t >> 6) == 0) HeT[HD][e] = f2b(1.0f);
    }
    // HeT/Bs consumption is ordered by the barriers inside the kt loop.

    f32x4 acc[4][2];
#pragma unroll
    for (int mi = 0; mi < 4; ++mi)
#pragma unroll
        for (int ni = 0; ni < 2; ++ni)
            acc[mi][ni] = (f32x4){0.f, 0.f, 0.f, 0.f};

    const int n0 = wave * 32;
    for (int kt = 0; kt <= HD; ++kt) {
        __syncthreads();  // prior b_frag reads done (and 1st iter: HeT ready)
        {   // stage Bs slab kt: fully coalesced 16B chunks
            const uint4* gp = (const uint4*)(w2t + kt * HD * HD);
            uint4 v[8];
#pragma unroll
            for (int c = 0; c < 8; ++c) v[c] = gp[c * 256 + t];
#pragma unroll
            for (int c = 0; c < 8; ++c) {
                int f = c * 256 + t;
                *(uint4*)&Bs[f >> 4][(f & 15) * 8] = v[c];
            }
        }
        __syncthreads();
        short8 bfrag[2][4];  // lane holds B[k = kb*32+quad*8+j][n = n0+ni*16+l16] = Bs[n][k..]
#pragma unroll
        for (int ni = 0; ni < 2; ++ni)
#pragma unroll
            for (int kb = 0; kb < 4; ++kb)
                bfrag[ni][kb] = *(const short8*)&Bs[n0 + ni * 16 + l16][kb * 32 + quad * 8];
#pragma unroll
        for (int mi = 0; mi < 4; ++mi) {
            ushort4 hv = *(const ushort4*)&HeT[kt][mi * 16 + quad * 4];
            float h0 = b2f(hv.x), h1 = b2f(hv.y), h2 = b2f(hv.z), h3 = b2f(hv.w);
#pragma unroll
            for (int ni = 0; ni < 2; ++ni) {
                f32x4 p = {0.f, 0.f, 0.f, 0.f};
#pragma unroll
                for (int kb = 0; kb < 4; ++kb)
                    p = __builtin_amdgcn_mfma_f32_16x16x32_bf16(afrag[mi][kb], bfrag[ni][kb], p, 0, 0, 0);
                acc[mi][ni][0] = fmaf(h0, p[0], acc[mi][ni][0]);
                acc[mi][ni][1] = fmaf(h1, p[1], acc[mi][ni][1]);
                acc[mi][ni][2] = fmaf(h2, p[2], acc[mi][ni][2]);
                acc[mi][ni][3] = fmaf(h3, p[3], acc[mi][ni][3]);
            }
        }
    }
    // scatter epilogue: C/D row e = mi*16 + quad*4 + r, col o = n0 + ni*16 + l16
#pragma unroll
    for (int mi = 0; mi < 4; ++mi) {
#pragma unroll
        for (int r = 0; r < 4; ++r) {
            const int dn = dst[e0 + mi * 16 + quad * 4 + r];
#pragma unroll
            for (int ni = 0; ni < 2; ++ni)
                atomicAdd(&agg[dn * HD + n0 + ni * 16 + l16], acc[mi][ni][r]);
        }
    }
}

// ---- node update layers 2/3 (IN PLACE): act 1 = elu, 2 = leaky_relu ----
__global__ __launch_bounds__(128) void node_update(
    float* __restrict__ agg, const float* __restrict__ cnt,
    const float* __restrict__ hprev, const float* __restrict__ root, const float* __restrict__ bias,
    const float* __restrict__ lng, const float* __restrict__ lnb, int act) {
    const int n = blockIdx.x, o = threadIdx.x;
    __shared__ float hr[HD];
    hr[o] = hprev[n * HD + o];
    __syncthreads();
    float s = bias[o];
#pragma unroll 8
    for (int k = 0; k < HD; ++k) s = fmaf(hr[k], root[k * HD + o], s);
    float v = agg[n * HD + o] / fmaxf(cnt[n], 1.0f) + s;
    __shared__ float red[2];
    float ws = wave_sum(v);
    if ((o & 63) == 0) red[o >> 6] = ws;
    __syncthreads();
    float m = (red[0] + red[1]) * (1.0f / HD);
    float d = v - m;
    float ws2 = wave_sum(d * d);
    __syncthreads();
    if ((o & 63) == 0) red[o >> 6] = ws2;
    __syncthreads();
    float var = (red[0] + red[1]) * (1.0f / HD);
    float y = d * rsqrtf(var + 1e-5f) * lng[o] + lnb[o];
    if (act == 1) y = (y > 0.0f) ? y : expm1f(y);
    else y = (y > 0.0f) ? y : 0.01f * y;
    agg[n * HD + o] = y;
}

// ---- pooling (mean/max per graph) + linear head; f32 out ---------------
__global__ __launch_bounds__(128) void pool_head(
    const float* __restrict__ h3, const int* __restrict__ batch,
    const float* __restrict__ cont, const float* __restrict__ ls,
    const float* __restrict__ lin_w, const float* __restrict__ lin_b, float* __restrict__ out) {
    const int g = blockIdx.x, o = threadIdx.x;
    float s = 0.0f, mx = -1e30f;
    int c = 0;
    for (int n = 0; n < N_NODES; ++n) {
        if (batch[n] == g) {
            float v = h3[n * HD + o];
            s += v;
            mx = fmaxf(mx, v);
            ++c;
        }
    }
    __shared__ float xcat[2 * HD + 5];
    xcat[o] = s / fmaxf((float)c, 1.0f);
    xcat[HD + o] = (c > 0) ? mx : 0.0f;
    if (o < 4) xcat[2 * HD + o] = cont[g * 4 + o];
    if (o == 0) xcat[2 * HD + 4] = ls[g];
    __syncthreads();
    if (o < 2) {
        float r = lin_b[o];
        for (int ri = 0; ri < 2 * HD + 5; ++ri) r = fmaf(xcat[ri], lin_w[ri * 2 + o], r);
        out[g * 2 + o] = r;
    }
}

extern "C" void kernel_launch(void* const* d_in, const int* in_sizes, int n_in,
                              void* d_out, int out_size, void* d_ws, size_t ws_size,
                              hipStream_t stream) {
    const float* x     = (const float*)d_in[0];
    const int*   ei    = (const int*)d_in[1];
    const float* ea    = (const float*)d_in[2];
    const int*   batch = (const int*)d_in[3];
    const float* cont  = (const float*)d_in[4];
    const float* ls    = (const float*)d_in[5];
    const float *c1_w1 = (const float*)d_in[6],  *c1_b1 = (const float*)d_in[7];
    const float *c1_w2 = (const float*)d_in[8],  *c1_b2 = (const float*)d_in[9];
    const float *c1_rt = (const float*)d_in[10], *c1_bs = (const float*)d_in[11];
    const float *c2_w1 = (const float*)d_in[12], *c2_b1 = (const float*)d_in[13];
    const float *c2_w2 = (const float*)d_in[14], *c2_b2 = (const float*)d_in[15];
    const float *c3_w1 = (const float*)d_in[18], *c3_b1 = (const float*)d_in[19];
    const float *c3_w2 = (const float*)d_in[20], *c3_b2 = (const float*)d_in[21];
    const float *c2_rt = (const float*)d_in[16], *c2_bs = (const float*)d_in[17];
    const float *c3_rt = (const float*)d_in[22], *c3_bs = (const float*)d_in[23];
    const float *ln1g = (const float*)d_in[24], *ln1b = (const float*)d_in[25];
    const float *ln2g = (const float*)d_in[26], *ln2b = (const float*)d_in[27];
    const float *ln3g = (const float*)d_in[28], *ln3b = (const float*)d_in[29];
    const float *lin_w = (const float*)d_in[30], *lin_b = (const float*)d_in[31];
    float* out = (float*)d_out;

    // workspace: cnt 16KB | bufA 2MB | bufB 2MB | w2t 4.23MB  => ~8.27 MB
    float*    cnt  = (float*)d_ws;
    float*    bufA = cnt + N_NODES;
    float*    bufB = bufA + N_NODES * HD;
    ushort_t* w2t  = (ushort_t*)(bufB + N_NODES * HD);
    const int* src = ei;
    const int* dst = ei + N_EDGES;

    hipMemsetAsync(cnt, 0, N_NODES * sizeof(float), stream);
    count_k<<<N_EDGES / 256, 256, 0, stream>>>(dst, cnt);

    // ---- layer 1 (VALU; small)
    hipMemsetAsync(bufA, 0, N_NODES * HD * sizeof(float), stream);
    l1_edge<<<N_EDGES / 4, 128, 0, stream>>>(x, src, dst, ea, c1_w1, c1_b1, c1_w2, c1_b2, bufA);
    node_update_l1<<<N_NODES, 128, 0, stream>>>(bufA, cnt, x, c1_rt, c1_bs, ln1g, ln1b);

    // ---- layer 2 (MFMA)
    w2t_prep<<<HD + 1, 256, 0, stream>>>(c2_w2, c2_b2, w2t);
    hipMemsetAsync(bufB, 0, N_NODES * HD * sizeof(float), stream);
    gemm_mfma<<<N_EDGES / BM, 256, 0, stream>>>(bufA, ea, c2_w1, c2_b1, w2t, src, dst, bufB);
    node_update<<<N_NODES, 128, 0, stream>>>(bufB, cnt, bufA, c2_rt, c2_bs, ln2g, ln2b, 1);

    // ---- layer 3 (MFMA, reuses w2t buffer)
    w2t_prep<<<HD + 1, 256, 0, stream>>>(c3_w2, c3_b2, w2t);
    hipMemsetAsync(bufA, 0, N_NODES * HD * sizeof(float), stream);
    gemm_mfma<<<N_EDGES / BM, 256, 0, stream>>>(bufB, ea, c3_w1, c3_b1, w2t, src, dst, bufA);
    node_update<<<N_NODES, 128, 0, stream>>>(bufA, cnt, bufB, c3_rt, c3_bs, ln3g, ln3b, 2);

    // ---- pool + head
    pool_head<<<N_GRAPHS, 128, 0, stream>>>(bufA, batch, cont, ls, lin_w, lin_b, out);
}

// Round 6
// 563.640 us; speedup vs baseline: 19.6576x; 1.3036x over previous
//
#include <hip/hip_runtime.h>
#include <hip/hip_bf16.h>

// Inputs f32 (proven R1/R4). Output f32.

#define N_NODES 4096
#define N_EDGES 16384
#define N_GRAPHS 16
#define HD 128   // hidden dim
#define BM 64    // edges per block in MFMA gemm
#define LDB 136  // padded LDS row stride in bf16 elems (272 B)

typedef unsigned short ushort_t;
typedef __attribute__((ext_vector_type(8))) short short8;  // 8 bf16 = 4 VGPR (MFMA A/B frag)
typedef __attribute__((ext_vector_type(4))) float f32x4;   // MFMA C/D frag

static __device__ __forceinline__ ushort_t f2b(float f) {
    __hip_bfloat16 h = __float2bfloat16(f);
    union { __hip_bfloat16 h; ushort_t u; } cv; cv.h = h; return cv.u;
}
static __device__ __forceinline__ float b2f(ushort_t u) {
    union { unsigned u; float f; } cv; cv.u = ((unsigned)u) << 16; return cv.f;
}

static __device__ __forceinline__ float wave_sum(float v) {
#pragma unroll
    for (int off = 1; off < 64; off <<= 1) v += __shfl_xor(v, off, 64);
    return v;
}

// ---- count incoming edges per node -------------------------------------
__global__ __launch_bounds__(256) void count_k(const int* __restrict__ dst, float* __restrict__ cnt) {
    int e = blockIdx.x * 256 + threadIdx.x;
    atomicAdd(&cnt[dst[e]], 1.0f);
}

// ---- layer 1 edge kernel (in_c = 3), f32 VALU (tiny) -------------------
__global__ __launch_bounds__(128) void l1_edge(
    const float* __restrict__ x, const int* __restrict__ src, const int* __restrict__ dst,
    const float* __restrict__ ea, const float* __restrict__ w1, const float* __restrict__ b1,
    const float* __restrict__ w2, const float* __restrict__ b2, float* __restrict__ agg) {
    __shared__ float h[4][HD];
    __shared__ float xsrc[4][3];
    const int o = threadIdx.x;
    const int e0 = blockIdx.x * 4;
#pragma unroll
    for (int q = 0; q < 4; ++q) {
        float s = b1[o];
#pragma unroll
        for (int j = 0; j < 4; ++j) s = fmaf(ea[(e0 + q) * 4 + j], w1[j * HD + o], s);
        h[q][o] = fmaxf(s, 0.0f);
    }
    if (o < 12) { int q = o / 3, i = o % 3; xsrc[q][i] = x[src[e0 + q] * 3 + i]; }
    __syncthreads();
    float acc[4] = {0.f, 0.f, 0.f, 0.f};
    for (int i = 0; i < 3; ++i) {
        float bb = b2[i * HD + o];
        float w[4] = {bb, bb, bb, bb};
        for (int k = 0; k < HD; ++k) {
            float w2v = w2[k * 384 + i * HD + o];
#pragma unroll
            for (int q = 0; q < 4; ++q) w[q] = fmaf(h[q][k], w2v, w[q]);
        }
#pragma unroll
        for (int q = 0; q < 4; ++q) acc[q] = fmaf(xsrc[q][i], w[q], acc[q]);
    }
#pragma unroll
    for (int q = 0; q < 4; ++q) atomicAdd(&agg[dst[e0 + q] * HD + o], acc[q]);
}

// ---- layer-1 node update (IN PLACE): agg := relu(LN(agg/cnt + x@root + b))
__global__ __launch_bounds__(128) void node_update_l1(
    float* __restrict__ agg, const float* __restrict__ cnt, const float* __restrict__ x,
    const float* __restrict__ root, const float* __restrict__ bias,
    const float* __restrict__ lng, const float* __restrict__ lnb) {
    const int n = blockIdx.x, o = threadIdx.x;
    float s = bias[o];
#pragma unroll
    for (int i = 0; i < 3; ++i) s = fmaf(x[n * 3 + i], root[i * HD + o], s);
    float v = agg[n * HD + o] / fmaxf(cnt[n], 1.0f) + s;
    __shared__ float red[2];
    float ws = wave_sum(v);
    if ((o & 63) == 0) red[o >> 6] = ws;
    __syncthreads();
    float m = (red[0] + red[1]) * (1.0f / HD);
    float d = v - m;
    float ws2 = wave_sum(d * d);
    __syncthreads();
    if ((o & 63) == 0) red[o >> 6] = ws2;
    __syncthreads();
    float var = (red[0] + red[1]) * (1.0f / HD);
    float y = d * rsqrtf(var + 1e-5f) * lng[o] + lnb[o];
    agg[n * HD + o] = fmaxf(y, 0.0f);
}

// ---- one-time transpose+convert: w2t[kt][o][i] = bf16(w2[kt][i][o]); kt=128 slab = b2
__global__ __launch_bounds__(256) void w2t_prep(const float* __restrict__ w2,
                                                const float* __restrict__ b2,
                                                ushort_t* __restrict__ w2t) {
    __shared__ ushort_t tile[HD][LDB];
    const int kt = blockIdx.x;  // 0..128
    const int t = threadIdx.x;
    const float* srcp = (kt < HD) ? (w2 + kt * HD * HD) : b2;
    for (int c = 0; c < 64; ++c) {
        int flat = c * 256 + t;          // 0..16383, coalesced over o
        int i = flat >> 7, o = flat & 127;
        tile[o][i] = f2b(srcp[i * HD + o]);
    }
    __syncthreads();
    uint4* outp = (uint4*)(w2t + kt * HD * HD);
    for (int c = 0; c < 8; ++c) {
        int f = c * 256 + t;             // 16B-chunk index, coalesced
        int o = f >> 4, i0 = (f & 15) * 8;
        outp[f] = *(const uint4*)&tile[o][i0];
    }
}

// ---- heavy layers 2/3: MFMA GEMM + he-scaling + atomic scatter ---------
__global__ __launch_bounds__(256) void gemm_mfma(
    const float* __restrict__ hprev, const float* __restrict__ ea,
    const float* __restrict__ w1, const float* __restrict__ b1,
    const ushort_t* __restrict__ w2t,
    const int* __restrict__ src, const int* __restrict__ dst,
    float* __restrict__ agg) {
    __shared__ ushort_t Bs[HD][LDB];      // w2t slab (transposed, bf16)
    __shared__ ushort_t Xs[BM][LDB];      // gathered source features (bf16)
    __shared__ ushort_t HeT[HD + 1][BM];  // edge-MLP outputs, [kt][e]
    __shared__ float    eas[BM][4];

    const int t = threadIdx.x;
    const int wave = t >> 6, lane = t & 63;
    const int quad = lane >> 4, l16 = lane & 15;
    const int e0 = blockIdx.x * BM;

    eas[t >> 2][t & 3] = ea[(e0 + (t >> 2)) * 4 + (t & 3)];

    {   // stage xs: thread -> (edge t>>2, 32 cols), f32 -> bf16
        const int le = t >> 2, i0 = (t & 3) * 32;
        const float* rp = hprev + src[e0 + le] * HD + i0;
        ushort_t tmp[32];
#pragma unroll
        for (int c = 0; c < 8; ++c) {
            float4 v = ((const float4*)rp)[c];
            tmp[c * 4 + 0] = f2b(v.x); tmp[c * 4 + 1] = f2b(v.y);
            tmp[c * 4 + 2] = f2b(v.z); tmp[c * 4 + 3] = f2b(v.w);
        }
#pragma unroll
        for (int c = 0; c < 4; ++c)
            *(uint4*)&Xs[le][i0 + c * 8] = *(const uint4*)&tmp[c * 8];
    }
    __syncthreads();

    short8 afrag[4][4];  // lane holds A[m=l16][k = kb*32 + quad*8 + j]
#pragma unroll
    for (int mi = 0; mi < 4; ++mi)
#pragma unroll
        for (int kb = 0; kb < 4; ++kb)
            afrag[mi][kb] = *(const short8*)&Xs[mi * 16 + l16][kb * 32 + quad * 8];

    {   // edge MLP -> HeT[kt][e] (bf16); kt=128 slab = 1.0 (bias term)
        const int e = t & 63;
        const float a0 = eas[e][0], a1 = eas[e][1], a2 = eas[e][2], a3 = eas[e][3];
        for (int kt = t >> 6; kt < HD; kt += 4) {
            float s = b1[kt];
            s = fmaf(a0, w1[0 * HD + kt], s);
            s = fmaf(a1, w1[1 * HD + kt], s);
            s = fmaf(a2, w1[2 * HD + kt], s);
            s = fmaf(a3, w1[3 * HD + kt], s);
            HeT[kt][e] = f2b(fmaxf(s, 0.0f));
        }
        if ((t >> 6) == 0) HeT[HD][e] = f2b(1.0f);
    }

    f32x4 acc[4][2];
#pragma unroll
    for (int mi = 0; mi < 4; ++mi)
#pragma unroll
        for (int ni = 0; ni < 2; ++ni)
            acc[mi][ni] = (f32x4){0.f, 0.f, 0.f, 0.f};

    const int n0 = wave * 32;
    for (int kt = 0; kt <= HD; ++kt) {
        __syncthreads();
        {   // stage Bs slab kt
            const uint4* gp = (const uint4*)(w2t + kt * HD * HD);
            uint4 v[8];
#pragma unroll
            for (int c = 0; c < 8; ++c) v[c] = gp[c * 256 + t];
#pragma unroll
            for (int c = 0; c < 8; ++c) {
                int f = c * 256 + t;
                *(uint4*)&Bs[f >> 4][(f & 15) * 8] = v[c];
            }
        }
        __syncthreads();
        short8 bfrag[2][4];
#pragma unroll
        for (int ni = 0; ni < 2; ++ni)
#pragma unroll
            for (int kb = 0; kb < 4; ++kb)
                bfrag[ni][kb] = *(const short8*)&Bs[n0 + ni * 16 + l16][kb * 32 + quad * 8];
#pragma unroll
        for (int mi = 0; mi < 4; ++mi) {
            ushort4 hv = *(const ushort4*)&HeT[kt][mi * 16 + quad * 4];
            float h0 = b2f(hv.x), h1 = b2f(hv.y), h2 = b2f(hv.z), h3 = b2f(hv.w);
#pragma unroll
            for (int ni = 0; ni < 2; ++ni) {
                f32x4 p = {0.f, 0.f, 0.f, 0.f};
#pragma unroll
                for (int kb = 0; kb < 4; ++kb)
                    p = __builtin_amdgcn_mfma_f32_16x16x32_bf16(afrag[mi][kb], bfrag[ni][kb], p, 0, 0, 0);
                acc[mi][ni][0] = fmaf(h0, p[0], acc[mi][ni][0]);
                acc[mi][ni][1] = fmaf(h1, p[1], acc[mi][ni][1]);
                acc[mi][ni][2] = fmaf(h2, p[2], acc[mi][ni][2]);
                acc[mi][ni][3] = fmaf(h3, p[3], acc[mi][ni][3]);
            }
        }
    }
#pragma unroll
    for (int mi = 0; mi < 4; ++mi) {
#pragma unroll
        for (int r = 0; r < 4; ++r) {
            const int dn = dst[e0 + mi * 16 + quad * 4 + r];
#pragma unroll
            for (int ni = 0; ni < 2; ++ni)
                atomicAdd(&agg[dn * HD + n0 + ni * 16 + l16], acc[mi][ni][r]);
        }
    }
}

// ---- node update layers 2/3 (IN PLACE): act 1 = elu, 2 = leaky_relu ----
__global__ __launch_bounds__(128) void node_update(
    float* __restrict__ agg, const float* __restrict__ cnt,
    const float* __restrict__ hprev, const float* __restrict__ root, const float* __restrict__ bias,
    const float* __restrict__ lng, const float* __restrict__ lnb, int act) {
    const int n = blockIdx.x, o = threadIdx.x;
    __shared__ float hr[HD];
    hr[o] = hprev[n * HD + o];
    __syncthreads();
    float s = bias[o];
#pragma unroll 8
    for (int k = 0; k < HD; ++k) s = fmaf(hr[k], root[k * HD + o], s);
    float v = agg[n * HD + o] / fmaxf(cnt[n], 1.0f) + s;
    __shared__ float red[2];
    float ws = wave_sum(v);
    if ((o & 63) == 0) red[o >> 6] = ws;
    __syncthreads();
    float m = (red[0] + red[1]) * (1.0f / HD);
    float d = v - m;
    float ws2 = wave_sum(d * d);
    __syncthreads();
    if ((o & 63) == 0) red[o >> 6] = ws2;
    __syncthreads();
    float var = (red[0] + red[1]) * (1.0f / HD);
    float y = d * rsqrtf(var + 1e-5f) * lng[o] + lnb[o];
    if (act == 1) y = (y > 0.0f) ? y : expm1f(y);
    else y = (y > 0.0f) ? y : 0.01f * y;
    agg[n * HD + o] = y;
}

// ---- pooling phase 1: scatter-reduce into per-graph sum/max/count ------
// float max via order-preserving uint mapping (handles negatives).
static __device__ __forceinline__ unsigned fkey(float f) {
    unsigned b = __float_as_uint(f);
    return (b & 0x80000000u) ? ~b : (b | 0x80000000u);
}
__global__ __launch_bounds__(256) void pool_scatter(
    const float* __restrict__ h3, const int* __restrict__ batch,
    float* __restrict__ gsum, unsigned* __restrict__ gmaxk, int* __restrict__ gcnt) {
    const int idx = blockIdx.x * 256 + threadIdx.x;   // over N_NODES*HD
    const int n = idx >> 7, o = idx & 127;
    const int g = batch[n];
    const float v = h3[idx];
    atomicAdd(&gsum[g * HD + o], v);
    atomicMax(&gmaxk[g * HD + o], fkey(v));
    if (o == 0) atomicAdd(&gcnt[g], 1);
}

// ---- pooling phase 2 + linear head; f32 out ----------------------------
__global__ __launch_bounds__(128) void pool_head2(
    const float* __restrict__ gsum, const unsigned* __restrict__ gmaxk, const int* __restrict__ gcnt,
    const float* __restrict__ cont, const float* __restrict__ ls,
    const float* __restrict__ lin_w, const float* __restrict__ lin_b, float* __restrict__ out) {
    const int g = blockIdx.x, o = threadIdx.x;
    const int c = gcnt[g];
    __shared__ float xcat[2 * HD + 5];
    xcat[o] = gsum[g * HD + o] / fmaxf((float)c, 1.0f);
    unsigned key = gmaxk[g * HD + o];
    unsigned bits = (key & 0x80000000u) ? (key & 0x7FFFFFFFu) : ~key;
    xcat[HD + o] = (c > 0) ? __uint_as_float(bits) : 0.0f;
    if (o < 4) xcat[2 * HD + o] = cont[g * 4 + o];
    if (o == 0) xcat[2 * HD + 4] = ls[g];
    __syncthreads();
    if (o < 2) {
        float r = lin_b[o];
        for (int ri = 0; ri < 2 * HD + 5; ++ri) r = fmaf(xcat[ri], lin_w[ri * 2 + o], r);
        out[g * 2 + o] = r;
    }
}

extern "C" void kernel_launch(void* const* d_in, const int* in_sizes, int n_in,
                              void* d_out, int out_size, void* d_ws, size_t ws_size,
                              hipStream_t stream) {
    const float* x     = (const float*)d_in[0];
    const int*   ei    = (const int*)d_in[1];
    const float* ea    = (const float*)d_in[2];
    const int*   batch = (const int*)d_in[3];
    const float* cont  = (const float*)d_in[4];
    const float* ls    = (const float*)d_in[5];
    const float *c1_w1 = (const float*)d_in[6],  *c1_b1 = (const float*)d_in[7];
    const float *c1_w2 = (const float*)d_in[8],  *c1_b2 = (const float*)d_in[9];
    const float *c1_rt = (const float*)d_in[10], *c1_bs = (const float*)d_in[11];
    const float *c2_w1 = (const float*)d_in[12], *c2_b1 = (const float*)d_in[13];
    const float *c2_w2 = (const float*)d_in[14], *c2_b2 = (const float*)d_in[15];
    const float *c2_rt = (const float*)d_in[16], *c2_bs = (const float*)d_in[17];
    const float *c3_w1 = (const float*)d_in[18], *c3_b1 = (const float*)d_in[19];
    const float *c3_w2 = (const float*)d_in[20], *c3_b2 = (const float*)d_in[21];
    const float *c3_rt = (const float*)d_in[22], *c3_bs = (const float*)d_in[23];
    const float *ln1g = (const float*)d_in[24], *ln1b = (const float*)d_in[25];
    const float *ln2g = (const float*)d_in[26], *ln2b = (const float*)d_in[27];
    const float *ln3g = (const float*)d_in[28], *ln3b = (const float*)d_in[29];
    const float *lin_w = (const float*)d_in[30], *lin_b = (const float*)d_in[31];
    float* out = (float*)d_out;

    // workspace: cnt 16KB | bufA 2MB | bufB 2MB | w2t 4.23MB | pool 16.5KB
    float*    cnt  = (float*)d_ws;
    float*    bufA = cnt + N_NODES;
    float*    bufB = bufA + N_NODES * HD;
    ushort_t* w2t  = (ushort_t*)(bufB + N_NODES * HD);
    float*    gsum = (float*)(w2t + (HD + 1) * HD * HD);
    unsigned* gmaxk = (unsigned*)(gsum + N_GRAPHS * HD);
    int*      gcnt = (int*)(gmaxk + N_GRAPHS * HD);
    const int* src = ei;
    const int* dst = ei + N_EDGES;

    hipMemsetAsync(cnt, 0, N_NODES * sizeof(float), stream);
    count_k<<<N_EDGES / 256, 256, 0, stream>>>(dst, cnt);

    // ---- layer 1 (VALU; small)
    hipMemsetAsync(bufA, 0, N_NODES * HD * sizeof(float), stream);
    l1_edge<<<N_EDGES / 4, 128, 0, stream>>>(x, src, dst, ea, c1_w1, c1_b1, c1_w2, c1_b2, bufA);
    node_update_l1<<<N_NODES, 128, 0, stream>>>(bufA, cnt, x, c1_rt, c1_bs, ln1g, ln1b);

    // ---- layer 2 (MFMA)
    w2t_prep<<<HD + 1, 256, 0, stream>>>(c2_w2, c2_b2, w2t);
    hipMemsetAsync(bufB, 0, N_NODES * HD * sizeof(float), stream);
    gemm_mfma<<<N_EDGES / BM, 256, 0, stream>>>(bufA, ea, c2_w1, c2_b1, w2t, src, dst, bufB);
    node_update<<<N_NODES, 128, 0, stream>>>(bufB, cnt, bufA, c2_rt, c2_bs, ln2g, ln2b, 1);

    // ---- layer 3 (MFMA, reuses w2t buffer)
    w2t_prep<<<HD + 1, 256, 0, stream>>>(c3_w2, c3_b2, w2t);
    hipMemsetAsync(bufA, 0, N_NODES * HD * sizeof(float), stream);
    gemm_mfma<<<N_EDGES / BM, 256, 0, stream>>>(bufB, ea, c3_w1, c3_b1, w2t, src, dst, bufA);
    node_update<<<N_NODES, 128, 0, stream>>>(bufA, cnt, bufB, c3_rt, c3_bs, ln3g, ln3b, 2);

    // ---- pool (scatter-reduce) + head
    hipMemsetAsync(gsum, 0, (2 * N_GRAPHS * HD + N_GRAPHS) * sizeof(float), stream);
    pool_scatter<<<N_NODES * HD / 256, 256, 0, stream>>>(bufA, batch, gsum, gmaxk, gcnt);
    pool_head2<<<N_GRAPHS, 128, 0, stream>>>(gsum, gmaxk, gcnt, cont, ls, lin_w, lin_b, out);
}

// Round 7
// 523.400 us; speedup vs baseline: 21.1689x; 1.0769x over previous
//
#include <hip/hip_runtime.h>
#include <hip/hip_bf16.h>

// Inputs f32 (proven R1/R4). Output f32.

#define N_NODES 4096
#define N_EDGES 16384
#define N_GRAPHS 16
#define HD 128   // hidden dim
#define BM 64    // edges per block in MFMA gemm
#define LDB 136  // padded LDS row stride in bf16 elems (272 B)

typedef unsigned short ushort_t;
typedef __attribute__((ext_vector_type(8))) short short8;  // 8 bf16 = 4 VGPR (MFMA A/B frag)
typedef __attribute__((ext_vector_type(4))) float f32x4;   // MFMA C/D frag

static __device__ __forceinline__ ushort_t f2b(float f) {
    __hip_bfloat16 h = __float2bfloat16(f);
    union { __hip_bfloat16 h; ushort_t u; } cv; cv.h = h; return cv.u;
}
static __device__ __forceinline__ float b2f(ushort_t u) {
    union { unsigned u; float f; } cv; cv.u = ((unsigned)u) << 16; return cv.f;
}

static __device__ __forceinline__ float wave_sum(float v) {
#pragma unroll
    for (int off = 1; off < 64; off <<= 1) v += __shfl_xor(v, off, 64);
    return v;
}

// ---- count incoming edges per node -------------------------------------
__global__ __launch_bounds__(256) void count_k(const int* __restrict__ dst, float* __restrict__ cnt) {
    int e = blockIdx.x * 256 + threadIdx.x;
    atomicAdd(&cnt[dst[e]], 1.0f);
}

// ---- layer 1 edge kernel (in_c = 3), f32 VALU (tiny) -------------------
__global__ __launch_bounds__(128) void l1_edge(
    const float* __restrict__ x, const int* __restrict__ src, const int* __restrict__ dst,
    const float* __restrict__ ea, const float* __restrict__ w1, const float* __restrict__ b1,
    const float* __restrict__ w2, const float* __restrict__ b2, float* __restrict__ agg) {
    __shared__ float h[4][HD];
    __shared__ float xsrc[4][3];
    const int o = threadIdx.x;
    const int e0 = blockIdx.x * 4;
#pragma unroll
    for (int q = 0; q < 4; ++q) {
        float s = b1[o];
#pragma unroll
        for (int j = 0; j < 4; ++j) s = fmaf(ea[(e0 + q) * 4 + j], w1[j * HD + o], s);
        h[q][o] = fmaxf(s, 0.0f);
    }
    if (o < 12) { int q = o / 3, i = o % 3; xsrc[q][i] = x[src[e0 + q] * 3 + i]; }
    __syncthreads();
    float acc[4] = {0.f, 0.f, 0.f, 0.f};
    for (int i = 0; i < 3; ++i) {
        float bb = b2[i * HD + o];
        float w[4] = {bb, bb, bb, bb};
        for (int k = 0; k < HD; ++k) {
            float w2v = w2[k * 384 + i * HD + o];
#pragma unroll
            for (int q = 0; q < 4; ++q) w[q] = fmaf(h[q][k], w2v, w[q]);
        }
#pragma unroll
        for (int q = 0; q < 4; ++q) acc[q] = fmaf(xsrc[q][i], w[q], acc[q]);
    }
#pragma unroll
    for (int q = 0; q < 4; ++q) atomicAdd(&agg[dst[e0 + q] * HD + o], acc[q]);
}

// ---- layer-1 node update (IN PLACE): agg := relu(LN(agg/cnt + x@root + b))
__global__ __launch_bounds__(128) void node_update_l1(
    float* __restrict__ agg, const float* __restrict__ cnt, const float* __restrict__ x,
    const float* __restrict__ root, const float* __restrict__ bias,
    const float* __restrict__ lng, const float* __restrict__ lnb) {
    const int n = blockIdx.x, o = threadIdx.x;
    float s = bias[o];
#pragma unroll
    for (int i = 0; i < 3; ++i) s = fmaf(x[n * 3 + i], root[i * HD + o], s);
    float v = agg[n * HD + o] / fmaxf(cnt[n], 1.0f) + s;
    __shared__ float red[2];
    float ws = wave_sum(v);
    if ((o & 63) == 0) red[o >> 6] = ws;
    __syncthreads();
    float m = (red[0] + red[1]) * (1.0f / HD);
    float d = v - m;
    float ws2 = wave_sum(d * d);
    __syncthreads();
    if ((o & 63) == 0) red[o >> 6] = ws2;
    __syncthreads();
    float var = (red[0] + red[1]) * (1.0f / HD);
    float y = d * rsqrtf(var + 1e-5f) * lng[o] + lnb[o];
    agg[n * HD + o] = fmaxf(y, 0.0f);
}

// ---- one-time transpose+convert: w2t[kt][o][i] = bf16(w2[kt][i][o]); kt=128 slab = b2
__global__ __launch_bounds__(256) void w2t_prep(const float* __restrict__ w2,
                                                const float* __restrict__ b2,
                                                ushort_t* __restrict__ w2t) {
    __shared__ ushort_t tile[HD][LDB];
    const int kt = blockIdx.x;  // 0..128
    const int t = threadIdx.x;
    const float* srcp = (kt < HD) ? (w2 + kt * HD * HD) : b2;
    for (int c = 0; c < 64; ++c) {
        int flat = c * 256 + t;          // 0..16383, coalesced over o
        int i = flat >> 7, o = flat & 127;
        tile[o][i] = f2b(srcp[i * HD + o]);
    }
    __syncthreads();
    uint4* outp = (uint4*)(w2t + kt * HD * HD);
    for (int c = 0; c < 8; ++c) {
        int f = c * 256 + t;             // 16B-chunk index, coalesced
        int o = f >> 4, i0 = (f & 15) * 8;
        outp[f] = *(const uint4*)&tile[o][i0];
    }
}

// ---- heavy layers 2/3: MFMA GEMM, B streamed straight from L2 ----------
// bfrag[ni][kb] for lane (l16,quad) = w2t[kt][n0+ni*16+l16][kb*32+quad*8 .. +7]
// -> one aligned global_load_dwordx4; NO LDS staging, NO barriers in kt loop.
__global__ __launch_bounds__(256) void gemm_mfma(
    const float* __restrict__ hprev, const float* __restrict__ ea,
    const float* __restrict__ w1, const float* __restrict__ b1,
    const ushort_t* __restrict__ w2t,
    const int* __restrict__ src, const int* __restrict__ dst,
    float* __restrict__ agg) {
    __shared__ ushort_t Xs[BM][LDB];      // gathered source features (bf16)
    __shared__ ushort_t HeT[HD + 1][BM];  // edge-MLP outputs, [kt][e]
    __shared__ float    eas[BM][4];

    const int t = threadIdx.x;
    const int wave = t >> 6, lane = t & 63;
    const int quad = lane >> 4, l16 = lane & 15;
    const int e0 = blockIdx.x * BM;
    const int n0 = wave * 32;

    eas[t >> 2][t & 3] = ea[(e0 + (t >> 2)) * 4 + (t & 3)];

    {   // stage xs: thread -> (edge t>>2, 32 cols), f32 -> bf16
        const int le = t >> 2, i0 = (t & 3) * 32;
        const float* rp = hprev + src[e0 + le] * HD + i0;
        ushort_t tmp[32];
#pragma unroll
        for (int c = 0; c < 8; ++c) {
            float4 v = ((const float4*)rp)[c];
            tmp[c * 4 + 0] = f2b(v.x); tmp[c * 4 + 1] = f2b(v.y);
            tmp[c * 4 + 2] = f2b(v.z); tmp[c * 4 + 3] = f2b(v.w);
        }
#pragma unroll
        for (int c = 0; c < 4; ++c)
            *(uint4*)&Xs[le][i0 + c * 8] = *(const uint4*)&tmp[c * 8];
    }
    __syncthreads();

    short8 afrag[4][4];  // lane holds A[m=l16][k = kb*32 + quad*8 + j]
#pragma unroll
    for (int mi = 0; mi < 4; ++mi)
#pragma unroll
        for (int kb = 0; kb < 4; ++kb)
            afrag[mi][kb] = *(const short8*)&Xs[mi * 16 + l16][kb * 32 + quad * 8];

    {   // edge MLP -> HeT[kt][e] (bf16); kt=128 slab = 1.0 (bias term)
        const int e = t & 63;
        const float a0 = eas[e][0], a1 = eas[e][1], a2 = eas[e][2], a3 = eas[e][3];
        for (int kt = t >> 6; kt < HD; kt += 4) {
            float s = b1[kt];
            s = fmaf(a0, w1[0 * HD + kt], s);
            s = fmaf(a1, w1[1 * HD + kt], s);
            s = fmaf(a2, w1[2 * HD + kt], s);
            s = fmaf(a3, w1[3 * HD + kt], s);
            HeT[kt][e] = f2b(fmaxf(s, 0.0f));
        }
        if ((t >> 6) == 0) HeT[HD][e] = f2b(1.0f);
    }
    __syncthreads();   // HeT ready; last barrier in the kernel

    f32x4 acc[4][2];
#pragma unroll
    for (int mi = 0; mi < 4; ++mi)
#pragma unroll
        for (int ni = 0; ni < 2; ++ni)
            acc[mi][ni] = (f32x4){0.f, 0.f, 0.f, 0.f};

    const ushort_t* bbase = w2t + (n0 + l16) * HD + quad * 8;

    // B-slab load (8x global_load_dwordx4) and consumer, ping-pong prefetched
#define LOADB(bf, kt)                                                           \
    {                                                                           \
        const ushort_t* p = bbase + (kt) * (HD * HD);                           \
        _Pragma("unroll") for (int ni = 0; ni < 2; ++ni)                        \
            _Pragma("unroll") for (int kb = 0; kb < 4; ++kb)                    \
                bf[ni][kb] = *(const short8*)(p + ni * 16 * HD + kb * 32);      \
    }
#define CONSUME(bf, kt)                                                         \
    {                                                                           \
        _Pragma("unroll") for (int mi = 0; mi < 4; ++mi) {                      \
            ushort4 hv = *(const ushort4*)&HeT[kt][mi * 16 + quad * 4];         \
            float h0 = b2f(hv.x), h1 = b2f(hv.y), h2 = b2f(hv.z), h3 = b2f(hv.w);\
            _Pragma("unroll") for (int ni = 0; ni < 2; ++ni) {                  \
                f32x4 p = {0.f, 0.f, 0.f, 0.f};                                 \
                _Pragma("unroll") for (int kb = 0; kb < 4; ++kb)                \
                    p = __builtin_amdgcn_mfma_f32_16x16x32_bf16(                \
                        afrag[mi][kb], bf[ni][kb], p, 0, 0, 0);                 \
                acc[mi][ni][0] = fmaf(h0, p[0], acc[mi][ni][0]);                \
                acc[mi][ni][1] = fmaf(h1, p[1], acc[mi][ni][1]);                \
                acc[mi][ni][2] = fmaf(h2, p[2], acc[mi][ni][2]);                \
                acc[mi][ni][3] = fmaf(h3, p[3], acc[mi][ni][3]);                \
            }                                                                   \
        }                                                                       \
    }

    short8 bf0[2][4], bf1[2][4];
    LOADB(bf0, 0);
    for (int kt = 0; kt < HD; kt += 2) {
        LOADB(bf1, kt + 1);
        CONSUME(bf0, kt);
        LOADB(bf0, (kt + 2 <= HD) ? kt + 2 : HD);
        CONSUME(bf1, kt + 1);
    }
    CONSUME(bf0, HD);   // bias slab (kt = 128)
#undef LOADB
#undef CONSUME

    // scatter epilogue: C/D row e = mi*16 + quad*4 + r, col o = n0 + ni*16 + l16
#pragma unroll
    for (int mi = 0; mi < 4; ++mi) {
#pragma unroll
        for (int r = 0; r < 4; ++r) {
            const int dn = dst[e0 + mi * 16 + quad * 4 + r];
#pragma unroll
            for (int ni = 0; ni < 2; ++ni)
                atomicAdd(&agg[dn * HD + n0 + ni * 16 + l16], acc[mi][ni][r]);
        }
    }
}

// ---- node update layers 2/3 (IN PLACE): act 1 = elu, 2 = leaky_relu ----
__global__ __launch_bounds__(128) void node_update(
    float* __restrict__ agg, const float* __restrict__ cnt,
    const float* __restrict__ hprev, const float* __restrict__ root, const float* __restrict__ bias,
    const float* __restrict__ lng, const float* __restrict__ lnb, int act) {
    const int n = blockIdx.x, o = threadIdx.x;
    __shared__ float hr[HD];
    hr[o] = hprev[n * HD + o];
    __syncthreads();
    float s = bias[o];
#pragma unroll 8
    for (int k = 0; k < HD; ++k) s = fmaf(hr[k], root[k * HD + o], s);
    float v = agg[n * HD + o] / fmaxf(cnt[n], 1.0f) + s;
    __shared__ float red[2];
    float ws = wave_sum(v);
    if ((o & 63) == 0) red[o >> 6] = ws;
    __syncthreads();
    float m = (red[0] + red[1]) * (1.0f / HD);
    float d = v - m;
    float ws2 = wave_sum(d * d);
    __syncthreads();
    if ((o & 63) == 0) red[o >> 6] = ws2;
    __syncthreads();
    float var = (red[0] + red[1]) * (1.0f / HD);
    float y = d * rsqrtf(var + 1e-5f) * lng[o] + lnb[o];
    if (act == 1) y = (y > 0.0f) ? y : expm1f(y);
    else y = (y > 0.0f) ? y : 0.01f * y;
    agg[n * HD + o] = y;
}

// ---- pooling phase 1: scatter-reduce into per-graph sum/max/count ------
static __device__ __forceinline__ unsigned fkey(float f) {
    unsigned b = __float_as_uint(f);
    return (b & 0x80000000u) ? ~b : (b | 0x80000000u);
}
__global__ __launch_bounds__(256) void pool_scatter(
    const float* __restrict__ h3, const int* __restrict__ batch,
    float* __restrict__ gsum, unsigned* __restrict__ gmaxk, int* __restrict__ gcnt) {
    const int idx = blockIdx.x * 256 + threadIdx.x;   // over N_NODES*HD
    const int n = idx >> 7, o = idx & 127;
    const int g = batch[n];
    const float v = h3[idx];
    atomicAdd(&gsum[g * HD + o], v);
    atomicMax(&gmaxk[g * HD + o], fkey(v));
    if (o == 0) atomicAdd(&gcnt[g], 1);
}

// ---- pooling phase 2 + linear head; f32 out ----------------------------
__global__ __launch_bounds__(128) void pool_head2(
    const float* __restrict__ gsum, const unsigned* __restrict__ gmaxk, const int* __restrict__ gcnt,
    const float* __restrict__ cont, const float* __restrict__ ls,
    const float* __restrict__ lin_w, const float* __restrict__ lin_b, float* __restrict__ out) {
    const int g = blockIdx.x, o = threadIdx.x;
    const int c = gcnt[g];
    __shared__ float xcat[2 * HD + 5];
    xcat[o] = gsum[g * HD + o] / fmaxf((float)c, 1.0f);
    unsigned key = gmaxk[g * HD + o];
    unsigned bits = (key & 0x80000000u) ? (key & 0x7FFFFFFFu) : ~key;
    xcat[HD + o] = (c > 0) ? __uint_as_float(bits) : 0.0f;
    if (o < 4) xcat[2 * HD + o] = cont[g * 4 + o];
    if (o == 0) xcat[2 * HD + 4] = ls[g];
    __syncthreads();
    if (o < 2) {
        float r = lin_b[o];
        for (int ri = 0; ri < 2 * HD + 5; ++ri) r = fmaf(xcat[ri], lin_w[ri * 2 + o], r);
        out[g * 2 + o] = r;
    }
}

extern "C" void kernel_launch(void* const* d_in, const int* in_sizes, int n_in,
                              void* d_out, int out_size, void* d_ws, size_t ws_size,
                              hipStream_t stream) {
    const float* x     = (const float*)d_in[0];
    const int*   ei    = (const int*)d_in[1];
    const float* ea    = (const float*)d_in[2];
    const int*   batch = (const int*)d_in[3];
    const float* cont  = (const float*)d_in[4];
    const float* ls    = (const float*)d_in[5];
    const float *c1_w1 = (const float*)d_in[6],  *c1_b1 = (const float*)d_in[7];
    const float *c1_w2 = (const float*)d_in[8],  *c1_b2 = (const float*)d_in[9];
    const float *c1_rt = (const float*)d_in[10], *c1_bs = (const float*)d_in[11];
    const float *c2_w1 = (const float*)d_in[12], *c2_b1 = (const float*)d_in[13];
    const float *c2_w2 = (const float*)d_in[14], *c2_b2 = (const float*)d_in[15];
    const float *c2_rt = (const float*)d_in[16], *c2_bs = (const float*)d_in[17];
    const float *c3_w1 = (const float*)d_in[18], *c3_b1 = (const float*)d_in[19];
    const float *c3_w2 = (const float*)d_in[20], *c3_b2 = (const float*)d_in[21];
    const float *c3_rt = (const float*)d_in[22], *c3_bs = (const float*)d_in[23];
    const float *ln1g = (const float*)d_in[24], *ln1b = (const float*)d_in[25];
    const float *ln2g = (const float*)d_in[26], *ln2b = (const float*)d_in[27];
    const float *ln3g = (const float*)d_in[28], *ln3b = (const float*)d_in[29];
    const float *lin_w = (const float*)d_in[30], *lin_b = (const float*)d_in[31];
    float* out = (float*)d_out;

    // workspace: cnt 16KB | bufA 2MB | bufB 2MB | w2t 4.23MB | pool 16.5KB
    float*    cnt  = (float*)d_ws;
    float*    bufA = cnt + N_NODES;
    float*    bufB = bufA + N_NODES * HD;
    ushort_t* w2t  = (ushort_t*)(bufB + N_NODES * HD);
    float*    gsum = (float*)(w2t + (HD + 1) * HD * HD);
    unsigned* gmaxk = (unsigned*)(gsum + N_GRAPHS * HD);
    int*      gcnt = (int*)(gmaxk + N_GRAPHS * HD);
    const int* src = ei;
    const int* dst = ei + N_EDGES;

    hipMemsetAsync(cnt, 0, N_NODES * sizeof(float), stream);
    count_k<<<N_EDGES / 256, 256, 0, stream>>>(dst, cnt);

    // ---- layer 1 (VALU; small)
    hipMemsetAsync(bufA, 0, N_NODES * HD * sizeof(float), stream);
    l1_edge<<<N_EDGES / 4, 128, 0, stream>>>(x, src, dst, ea, c1_w1, c1_b1, c1_w2, c1_b2, bufA);
    node_update_l1<<<N_NODES, 128, 0, stream>>>(bufA, cnt, x, c1_rt, c1_bs, ln1g, ln1b);

    // ---- layer 2 (MFMA)
    w2t_prep<<<HD + 1, 256, 0, stream>>>(c2_w2, c2_b2, w2t);
    hipMemsetAsync(bufB, 0, N_NODES * HD * sizeof(float), stream);
    gemm_mfma<<<N_EDGES / BM, 256, 0, stream>>>(bufA, ea, c2_w1, c2_b1, w2t, src, dst, bufB);
    node_update<<<N_NODES, 128, 0, stream>>>(bufB, cnt, bufA, c2_rt, c2_bs, ln2g, ln2b, 1);

    // ---- layer 3 (MFMA, reuses w2t buffer)
    w2t_prep<<<HD + 1, 256, 0, stream>>>(c3_w2, c3_b2, w2t);
    hipMemsetAsync(bufA, 0, N_NODES * HD * sizeof(float), stream);
    gemm_mfma<<<N_EDGES / BM, 256, 0, stream>>>(bufB, ea, c3_w1, c3_b1, w2t, src, dst, bufA);
    node_update<<<N_NODES, 128, 0, stream>>>(bufA, cnt, bufB, c3_rt, c3_bs, ln3g, ln3b, 2);

    // ---- pool (scatter-reduce) + head
    hipMemsetAsync(gsum, 0, (2 * N_GRAPHS * HD + N_GRAPHS) * sizeof(float), stream);
    pool_scatter<<<N_NODES * HD / 256, 256, 0, stream>>>(bufA, batch, gsum, gmaxk, gcnt);
    pool_head2<<<N_GRAPHS, 128, 0, stream>>>(gsum, gmaxk, gcnt, cont, ls, lin_w, lin_b, out);
}